// Round 1
// baseline (247.771 us; speedup 1.0000x reference)
//
#include <hip/hip_runtime.h>
#include <hip/hip_bf16.h>

#define S_NODES 8192
#define P_PATHS 16
#define K_EP    16
#define D_DIM   128
#define H_DIM   64

typedef __bf16 bf16x8_t __attribute__((ext_vector_type(8)));
typedef float  f32x4_t  __attribute__((ext_vector_type(4)));

// LDS row strides chosen for <=2-way bank aliasing (free) + 16B alignment where b128 reads happen
#define AGGF_STRIDE  132   // floats
#define AGGBF_STRIDE 136   // bf16 (272B rows, 16B aligned)
#define W1T_STRIDE   136   // bf16 (272B rows, 16B aligned)

__global__ __launch_bounds__(256)
void PathGuidedAggregator_kernel(const float* __restrict__ ent,
                                 const float* __restrict__ W1,
                                 const float* __restrict__ b1,
                                 const float* __restrict__ W2,
                                 const float* __restrict__ b2,
                                 const int*   __restrict__ sids,
                                 const int*   __restrict__ eids,
                                 const void*  __restrict__ emask,
                                 float*       __restrict__ out)
{
    __shared__ float  aggf [P_PATHS][AGGF_STRIDE];   // fp32 agg (for w*agg, full precision)
    __shared__ __bf16 aggbf[P_PATHS][AGGBF_STRIDE];  // bf16 agg (MFMA A operand)
    __shared__ __bf16 w1t  [H_DIM][W1T_STRIDE];      // W1 transposed [j][d], bf16 (MFMA B operand)
    __shared__ float  b1s[H_DIM];
    __shared__ float  w2s[H_DIM];
    __shared__ int    cnts[P_PATHS];

    const int s    = blockIdx.x;
    const int tid  = threadIdx.x;
    const int wave = tid >> 6;
    const int lane = tid & 63;

    // ---- stage W1 (transposed -> bf16), b1, W2 into LDS ----
    #pragma unroll
    for (int it = 0; it < 32; ++it) {
        int idx = tid + it * 256;            // coalesced read of W1[d][j]
        int d = idx >> 6, j = idx & 63;
        w1t[j][d] = (__bf16)W1[idx];
    }
    if (tid < H_DIM) { b1s[tid] = b1[tid]; w2s[tid] = W2[tid]; }

    // ---- runtime detection of bool-mask storage: int32 / uint8 / float32 ----
    const unsigned int* mw = (const unsigned int*)emask;
    unsigned int probe = mw[lane];
    const bool floatMask = (__ballot(probe == 0x3F800000u) != 0ULL);
    const bool byteMask  = !floatMask && (__ballot(probe > 1u) != 0ULL);

    // ---- gather: wave w handles paths 4w..4w+3; lane owns dims (2*lane, 2*lane+1) ----
    #pragma unroll
    for (int i = 0; i < 4; ++i) {
        const int p    = wave * 4 + i;
        const int base = (s * P_PATHS + p) * K_EP;
        int idv = 0, mkv = 0;
        if (lane < K_EP) {
            idv = eids[base + lane];
            if (floatMask)     mkv = (((const float*)emask)[base + lane] != 0.0f);
            else if (byteMask) mkv = ((const unsigned char*)emask)[base + lane];
            else               mkv = ((const int*)emask)[base + lane];
        }
        unsigned long long bits = __ballot(lane < K_EP && mkv != 0);
        const int cnt = __popcll(bits);
        float ax = 0.f, ay = 0.f;
        // uniform bit-scan, 2 loads in flight to cover L2/L3 latency
        while (bits) {
            int k0 = __builtin_ctzll(bits); bits &= bits - 1;
            bool has2 = (bits != 0ULL);
            int k1 = has2 ? __builtin_ctzll(bits) : k0;
            if (has2) bits &= bits - 1;
            int id0 = __shfl(idv, k0);
            int id1 = __shfl(idv, k1);
            float2 v0 = ((const float2*)(ent + (size_t)id0 * D_DIM))[lane];
            float2 v1 = ((const float2*)(ent + (size_t)id1 * D_DIM))[lane];
            ax += v0.x; ay += v0.y;
            if (has2) { ax += v1.x; ay += v1.y; }
        }
        const float inv = 1.0f / (float)(cnt > 1 ? cnt : 1);
        ax *= inv; ay *= inv;
        *(float2*)&aggf[p][2 * lane] = make_float2(ax, ay);
        union { __bf16 h[2]; unsigned int u; } pk;
        pk.h[0] = (__bf16)ax; pk.h[1] = (__bf16)ay;
        *(unsigned int*)&aggbf[p][2 * lane] = pk.u;
        if (lane == 0) cnts[p] = cnt;
    }
    __syncthreads();

    if (wave != 0) return;

    // ---- MLP for all 16 paths at once via MFMA (wave 0 only) ----
    // A[m][k]: m = lane&15, k = (lane>>4)*8 + j   (16x16x32 bf16 A-layout)
    // B[k][n]: n = lane&15, k = (lane>>4)*8 + j
    // D[m][n]: n = lane&15, m = (lane>>4)*4 + reg
    const int m    = lane & 15;
    const int quad = lane >> 4;

    bf16x8_t afr[4];
    #pragma unroll
    for (int st = 0; st < 4; ++st)
        afr[st] = *(const bf16x8_t*)&aggbf[m][st * 32 + quad * 8];

    float xp[4] = {0.f, 0.f, 0.f, 0.f};
    #pragma unroll
    for (int t = 0; t < 4; ++t) {              // j-tile (16 cols each)
        const int n = t * 16 + m;
        const float b1v = b1s[n];
        f32x4_t acc = {b1v, b1v, b1v, b1v};    // fold b1 into C-init
        #pragma unroll
        for (int st = 0; st < 4; ++st) {       // K-steps of 32
            bf16x8_t bfr = *(const bf16x8_t*)&w1t[n][st * 32 + quad * 8];
            acc = __builtin_amdgcn_mfma_f32_16x16x32_bf16(afr[st], bfr, acc, 0, 0, 0);
        }
        const float w2v = w2s[n];
        #pragma unroll
        for (int r = 0; r < 4; ++r) {
            float h = acc[r] > 0.f ? acc[r] : 0.f;   // relu
            xp[r] += h * w2v;
        }
    }
    // reduce over the 16 lanes of each quad (sum over n)
    #pragma unroll
    for (int off = 1; off < 16; off <<= 1) {
        #pragma unroll
        for (int r = 0; r < 4; ++r) xp[r] += __shfl_xor(xp[r], off);
    }

    int myc[4]; int localv = 0;
    #pragma unroll
    for (int r = 0; r < 4; ++r) { myc[r] = cnts[quad * 4 + r]; localv += (myc[r] > 0); }
    int nv = localv + __shfl_xor(localv, 16);
    nv += __shfl_xor(nv, 32);
    const float invnv = 1.0f / (float)(nv > 1 ? nv : 1);
    const float b2v = b2[0];

    float wv[4];
    #pragma unroll
    for (int r = 0; r < 4; ++r) {
        float x = xp[r] + b2v;
        float w = 1.0f / (1.0f + __expf(-x));
        wv[r] = (myc[r] > 0) ? w * invnv : 0.f;   // invalid paths contribute 0
    }

    // broadcast all 16 path weights, accumulate node feature (fp32 agg)
    float fx = 0.f, fy = 0.f;
    #pragma unroll
    for (int p = 0; p < P_PATHS; ++p) {
        float wp = __shfl(wv[p & 3], (p >> 2) << 4);
        float2 a = *(const float2*)&aggf[p][2 * lane];
        fx += wp * a.x; fy += wp * a.y;
    }
    const int row = sids[s];
    *(float2*)&out[(size_t)row * D_DIM + 2 * lane] = make_float2(fx, fy);
}

extern "C" void kernel_launch(void* const* d_in, const int* in_sizes, int n_in,
                              void* d_out, int out_size, void* d_ws, size_t ws_size,
                              hipStream_t stream)
{
    const float* ent  = (const float*)d_in[0];
    const float* W1   = (const float*)d_in[1];
    const float* b1   = (const float*)d_in[2];
    const float* W2   = (const float*)d_in[3];
    const float* b2   = (const float*)d_in[4];
    const int*   sids = (const int*)d_in[5];
    const int*   eids = (const int*)d_in[6];
    const void*  emsk = (const void*)d_in[7];
    float* out = (float*)d_out;

    // zero the whole [N,D] output (rows not hit by the scatter must be 0; d_out is poisoned)
    hipMemsetAsync(d_out, 0, (size_t)out_size * sizeof(float), stream);
    PathGuidedAggregator_kernel<<<S_NODES, 256, 0, stream>>>(ent, W1, b1, W2, b2, sids, eids, emsk, out);
}